// Round 2
// baseline (1555.914 us; speedup 1.0000x reference)
//
#include <hip/hip_runtime.h>
#include <hip/hip_bf16.h>

#define DEV __device__ __forceinline__

DEV float sigmoidf_(float x) { return 1.0f / (1.0f + __expf(-x)); }

// ---------------------------------------------------------------------------
// Generic tiled fp32 GEMM: C[m][n] = act( sum_k A[m*lda+k] * W[n*ldw+k] + bias[n] )
// ACT: 0 = none, 1 = relu, 2 = softplus
// Requires: M%BM==0, N%BN==0, K%BK==0, blockDim=256, (BM/TM)*(BN/TN)==256
// ---------------------------------------------------------------------------
template<int BM, int BN, int BK, int TM, int TN, int ACT>
__global__ __launch_bounds__(256)
void gemm_kernel(const float* __restrict__ A, int lda,
                 const float* __restrict__ W, int ldw,
                 const float* __restrict__ bias,
                 float* __restrict__ C, int ldc,
                 int M, int N, int K)
{
    __shared__ float As[BK][BM + 4];
    __shared__ float Bs[BK][BN + 4];

    const int tid = threadIdx.x;
    constexpr int nTx = BN / TN;
    const int tx = tid % nTx;
    const int ty = tid / nTx;
    const int m0 = blockIdx.y * BM;
    const int n0 = blockIdx.x * BN;

    float acc[TM][TN];
#pragma unroll
    for (int i = 0; i < TM; ++i)
#pragma unroll
        for (int j = 0; j < TN; ++j) acc[i][j] = 0.0f;

    constexpr int KQ = BK / 4;               // float4 per row of the k-tile
    constexpr int A4 = BM * BK / (256 * 4);  // float4 loads per thread (A)
    constexpr int B4 = BN * BK / (256 * 4);  // float4 loads per thread (B)

    for (int k0 = 0; k0 < K; k0 += BK) {
#pragma unroll
        for (int i = 0; i < A4; ++i) {
            int idx = tid + i * 256;
            int m = idx / KQ;
            int kq = idx % KQ;
            const float4 v = *reinterpret_cast<const float4*>(
                &A[(size_t)(m0 + m) * lda + k0 + kq * 4]);
            As[kq * 4 + 0][m] = v.x;
            As[kq * 4 + 1][m] = v.y;
            As[kq * 4 + 2][m] = v.z;
            As[kq * 4 + 3][m] = v.w;
        }
#pragma unroll
        for (int i = 0; i < B4; ++i) {
            int idx = tid + i * 256;
            int n = idx / KQ;
            int kq = idx % KQ;
            const float4 v = *reinterpret_cast<const float4*>(
                &W[(size_t)(n0 + n) * ldw + k0 + kq * 4]);
            Bs[kq * 4 + 0][n] = v.x;
            Bs[kq * 4 + 1][n] = v.y;
            Bs[kq * 4 + 2][n] = v.z;
            Bs[kq * 4 + 3][n] = v.w;
        }
        __syncthreads();

#pragma unroll
        for (int k = 0; k < BK; ++k) {
            float a[TM], b[TN];
#pragma unroll
            for (int i = 0; i < TM; i += 4) {
                float4 v = *reinterpret_cast<const float4*>(&As[k][ty * TM + i]);
                a[i] = v.x; a[i + 1] = v.y; a[i + 2] = v.z; a[i + 3] = v.w;
            }
#pragma unroll
            for (int j = 0; j < TN; j += 4) {
                float4 v = *reinterpret_cast<const float4*>(&Bs[k][tx * TN + j]);
                b[j] = v.x; b[j + 1] = v.y; b[j + 2] = v.z; b[j + 3] = v.w;
            }
#pragma unroll
            for (int i = 0; i < TM; ++i)
#pragma unroll
                for (int j = 0; j < TN; ++j)
                    acc[i][j] = fmaf(a[i], b[j], acc[i][j]);
        }
        __syncthreads();
    }

#pragma unroll
    for (int i = 0; i < TM; ++i) {
        int row = m0 + ty * TM + i;
#pragma unroll
        for (int j = 0; j < TN; ++j) {
            int col = n0 + tx * TN + j;
            float v = acc[i][j] + (bias ? bias[col] : 0.0f);
            if (ACT == 1) v = fmaxf(v, 0.0f);
            else if (ACT == 2) v = fmaxf(v, 0.0f) + log1pf(__expf(-fabsf(v)));
            C[(size_t)row * ldc + col] = v;
        }
    }
}

#define CHUNK 32
#define DSTATE 16

// ---------------------------------------------------------------------------
// Depthwise causal conv (k=4) + bias + silu.  xmr: piece-local (R x 1024).
// grid: (NB * L/32, 4), block 256. Each thread: one d, 32 consecutive t.
// ---------------------------------------------------------------------------
__global__ __launch_bounds__(256)
void conv_silu_kernel(const float* __restrict__ xmr, const float* __restrict__ cw,
                      const float* __restrict__ cb, float* __restrict__ xms,
                      int L)
{
    const int NC = L / CHUNK;
    const int bc = blockIdx.x;
    const int c = bc % NC;
    const int b = bc / NC;            // piece-local batch index
    const int d = blockIdx.y * 256 + threadIdx.x;

    const float w0 = cw[d * 4 + 0], w1 = cw[d * 4 + 1];
    const float w2 = cw[d * 4 + 2], w3 = cw[d * 4 + 3];
    const float bb = cb[d];

    const int t0 = c * CHUNK;
    float x0 = 0.f, x1 = 0.f, x2 = 0.f;
    if (t0 >= 3) {   // t0 multiple of 32; only t0==0 lacks history (per batch)
        x0 = xmr[(size_t)(b * L + t0 - 3) * 1024 + d];
        x1 = xmr[(size_t)(b * L + t0 - 2) * 1024 + d];
        x2 = xmr[(size_t)(b * L + t0 - 1) * 1024 + d];
    }
    for (int t = t0; t < t0 + CHUNK; ++t) {
        float x3 = xmr[(size_t)(b * L + t) * 1024 + d];
        float v = fmaf(w0, x0, fmaf(w1, x1, fmaf(w2, x2, fmaf(w3, x3, bb))));
        xms[(size_t)(b * L + t) * 1024 + d] = v * sigmoidf_(v);
        x0 = x1; x1 = x2; x2 = x3;
    }
}

// ---------------------------------------------------------------------------
// Selective-scan pass 1: per chunk, P = prod(dA), S = local scan end.
// Layout of P/S: [b][chunk][s][d]  (d fastest). grid: (NB*NC, 4), block 256.
// ---------------------------------------------------------------------------
__global__ __launch_bounds__(256)
void scan_pass1(const float* __restrict__ delta, const float* __restrict__ xms,
                const float* __restrict__ dbl, const float* __restrict__ A_log,
                float* __restrict__ P, float* __restrict__ S, int L)
{
    const int NC = L / CHUNK;
    const int bc = blockIdx.x;
    const int c = bc % NC;
    const int b = bc / NC;
    const int d = blockIdx.y * 256 + threadIdx.x;

    __shared__ float Bsh[CHUNK][DSTATE];
#pragma unroll
    for (int it = 0; it < CHUNK * DSTATE / 256; ++it) {
        int idx = threadIdx.x + it * 256;
        int t = idx / DSTATE, s = idx % DSTATE;
        Bsh[t][s] = dbl[(size_t)(b * L + c * CHUNK + t) * 64 + 32 + s];
    }
    __syncthreads();

    float As_[DSTATE];
#pragma unroll
    for (int s = 0; s < DSTATE; ++s) As_[s] = -expf(A_log[d * DSTATE + s]);

    float h[DSTATE], p[DSTATE];
#pragma unroll
    for (int s = 0; s < DSTATE; ++s) { h[s] = 0.f; p[s] = 1.f; }

    for (int t = 0; t < CHUNK; ++t) {
        size_t row = (size_t)(b * L + c * CHUNK + t);
        float de = delta[row * 1024 + d];
        float x = xms[row * 1024 + d];
        float dx = de * x;
#pragma unroll
        for (int s = 0; s < DSTATE; ++s) {
            float dA = __expf(de * As_[s]);
            h[s] = fmaf(dA, h[s], dx * Bsh[t][s]);
            p[s] *= dA;
        }
    }
#pragma unroll
    for (int s = 0; s < DSTATE; ++s) {
        size_t o = ((size_t)(b * NC + c) * DSTATE + s) * 1024 + d;
        P[o] = p[s];
        S[o] = h[s];
    }
}

// ---------------------------------------------------------------------------
// Pass 2: sequential combine over chunks, emits chunk-initial states.
// Hinit MAY ALIAS P (read-before-write). grid: NB*64 blocks of 256.
// ---------------------------------------------------------------------------
__global__ __launch_bounds__(256)
void scan_pass2(const float* P, const float* __restrict__ S,
                float* Hinit, int NC)
{
    int g = blockIdx.x * 256 + threadIdx.x;
    int d = g % 1024;
    int s = (g / 1024) % DSTATE;
    int b = g / (1024 * DSTATE);
    float h = 0.f;
    for (int c = 0; c < NC; ++c) {
        size_t o = ((size_t)(b * NC + c) * DSTATE + s) * 1024 + d;
        float p = P[o];
        float sv = S[o];
        Hinit[o] = h;                 // overwrites P[o] AFTER both loads
        h = fmaf(p, h, sv);
    }
}

// ---------------------------------------------------------------------------
// Pass 3: recompute local scan from Hinit, y = (sum_s h*C + xm*D) * silu(z).
// Y MAY ALIAS delta (same-element read-then-write per thread).
// grid: (NB*NC, 4), block 256.
// ---------------------------------------------------------------------------
__global__ __launch_bounds__(256)
void scan_pass3(const float* delta, const float* __restrict__ xms,
                const float* __restrict__ dbl, const float* __restrict__ A_log,
                const float* __restrict__ Hinit, const float* __restrict__ Dp,
                const float* __restrict__ zbuf, float* Y, int L)
{
    const int NC = L / CHUNK;
    const int bc = blockIdx.x;
    const int c = bc % NC;
    const int b = bc / NC;
    const int d = blockIdx.y * 256 + threadIdx.x;

    __shared__ float Bsh[CHUNK][DSTATE];
    __shared__ float Csh[CHUNK][DSTATE];
#pragma unroll
    for (int it = 0; it < CHUNK * DSTATE / 256; ++it) {
        int idx = threadIdx.x + it * 256;
        int t = idx / DSTATE, s = idx % DSTATE;
        size_t base = (size_t)(b * L + c * CHUNK + t) * 64;
        Bsh[t][s] = dbl[base + 32 + s];
        Csh[t][s] = dbl[base + 48 + s];
    }
    __syncthreads();

    float As_[DSTATE];
#pragma unroll
    for (int s = 0; s < DSTATE; ++s) As_[s] = -expf(A_log[d * DSTATE + s]);

    float h[DSTATE];
#pragma unroll
    for (int s = 0; s < DSTATE; ++s)
        h[s] = Hinit[((size_t)(b * NC + c) * DSTATE + s) * 1024 + d];

    const float Dd = Dp[d];
    for (int t = 0; t < CHUNK; ++t) {
        size_t row = (size_t)(b * L + c * CHUNK + t);
        float de = delta[row * 1024 + d];
        float x = xms[row * 1024 + d];
        float dx = de * x;
        float y = 0.f;
#pragma unroll
        for (int s = 0; s < DSTATE; ++s) {
            float dA = __expf(de * As_[s]);
            h[s] = fmaf(dA, h[s], dx * Bsh[t][s]);
            y = fmaf(h[s], Csh[t][s], y);
        }
        y = fmaf(x, Dd, y);
        float z = zbuf[row * 1024 + d];
        Y[row * 1024 + d] = y * (z * sigmoidf_(z));
    }
}

// ---------------------------------------------------------------------------

extern "C" void kernel_launch(void* const* d_in, const int* in_sizes, int n_in,
                              void* d_out, int out_size, void* d_ws, size_t ws_size,
                              hipStream_t stream)
{
    (void)in_sizes; (void)n_in; (void)out_size;

    const float* x         = (const float*)d_in[0];
    const float* enc_w1    = (const float*)d_in[1];
    const float* enc_b1    = (const float*)d_in[2];
    const float* enc_w2    = (const float*)d_in[3];
    const float* enc_b2    = (const float*)d_in[4];
    const float* in_proj_w = (const float*)d_in[5];
    const float* conv_w    = (const float*)d_in[6];
    const float* conv_b    = (const float*)d_in[7];
    const float* x_proj_w  = (const float*)d_in[8];
    const float* dt_proj_w = (const float*)d_in[9];
    const float* dt_proj_b = (const float*)d_in[10];
    const float* A_log     = (const float*)d_in[11];
    const float* D_param   = (const float*)d_in[12];
    const float* out_proj_w= (const float*)d_in[13];
    const float* dec_w1    = (const float*)d_in[14];
    const float* dec_b1    = (const float*)d_in[15];
    const float* dec_w2    = (const float*)d_in[16];
    const float* dec_b2    = (const float*)d_in[17];
    float* out = (float*)d_out;

    const int B = 8, L = 2048, NC = L / CHUNK;   // NC = 64

    // Footprint: 4928 floats per row (19,712 B). Pick smallest batch-split
    // whose piece fits ws_size. (ws_size is constant across calls ->
    // graph-capture stable.)
    const size_t PER_ROW = 4928 * sizeof(float);
    int SPLIT = 8;
    if      (ws_size >= (size_t)16384 * PER_ROW) SPLIT = 1;
    else if (ws_size >= (size_t) 8192 * PER_ROW) SPLIT = 2;
    else if (ws_size >= (size_t) 4096 * PER_ROW) SPLIT = 4;

    const int NB = B / SPLIT;          // batches per piece
    const int MR = NB * L;             // rows per piece

    // Piece-local buffer offsets (floats)
    float* ws   = (float*)d_ws;
    float* hbuf = ws;                           // MR x 256   (reused: h2)
    float* ubuf = hbuf + (size_t)MR * 256;      // MR x 512   (reused: o)
    float* cbuf = ubuf + (size_t)MR * 512;      // MR x 1024  xm_raw -> delta -> y
    float* zbuf = cbuf + (size_t)MR * 1024;     // MR x 1024  z
    float* xms  = zbuf + (size_t)MR * 1024;     // MR x 1024  silu(conv(xm))
    float* dbl  = xms  + (size_t)MR * 1024;     // MR x 64    [dt|B|C]
    float* P    = dbl  + (size_t)MR * 64;       // MR x 512 = NB*NC*16*1024 (-> Hinit)
    float* S    = P    + (size_t)MR * 512;      // MR x 512

    dim3 blk(256);

    for (int p = 0; p < SPLIT; ++p) {
        const int b0 = p * NB;
        const float* xp  = x   + (size_t)b0 * L * 64;
        float*       outp= out + (size_t)b0 * L * 64;

        // 1. enc1: h = relu(x @ enc_w1^T + b1)      (MR x 256), K=64
        gemm_kernel<128,128,16,8,8,1><<<dim3(2, MR/128), blk, 0, stream>>>(
            xp, 64, enc_w1, 64, enc_b1, hbuf, 256, MR, 256, 64);
        // 2. enc2: u = h @ enc_w2^T + b2            (MR x 512), K=256
        gemm_kernel<128,128,16,8,8,0><<<dim3(4, MR/128), blk, 0, stream>>>(
            hbuf, 256, enc_w2, 256, enc_b2, ubuf, 512, MR, 512, 256);
        // 3a. in_proj (xm half): cbuf = u @ W[0:1024]^T
        gemm_kernel<128,128,16,8,8,0><<<dim3(8, MR/128), blk, 0, stream>>>(
            ubuf, 512, in_proj_w, 512, nullptr, cbuf, 1024, MR, 1024, 512);
        // 3b. in_proj (z half): zbuf = u @ W[1024:2048]^T
        gemm_kernel<128,128,16,8,8,0><<<dim3(8, MR/128), blk, 0, stream>>>(
            ubuf, 512, in_proj_w + (size_t)1024 * 512, 512, nullptr,
            zbuf, 1024, MR, 1024, 512);
        // 4. conv + silu -> xms
        conv_silu_kernel<<<dim3(NB * NC, 4), blk, 0, stream>>>(
            cbuf, conv_w, conv_b, xms, L);
        // 5. x_proj: dbl = xms @ x_proj_w^T         (MR x 64), K=1024
        gemm_kernel<64,64,16,4,4,0><<<dim3(1, MR/64), blk, 0, stream>>>(
            xms, 1024, x_proj_w, 1024, nullptr, dbl, 64, MR, 64, 1024);
        // 6. dt_proj + softplus: delta (over cbuf)  (MR x 1024), K=32
        gemm_kernel<128,128,16,8,8,2><<<dim3(8, MR/128), blk, 0, stream>>>(
            dbl, 64, dt_proj_w, 32, dt_proj_b, cbuf, 1024, MR, 1024, 32);
        // 7-9. selective scan
        scan_pass1<<<dim3(NB * NC, 4), blk, 0, stream>>>(
            cbuf, xms, dbl, A_log, P, S, L);
        scan_pass2<<<dim3(NB * 64), blk, 0, stream>>>(P, S, P /*Hinit in place*/, NC);
        scan_pass3<<<dim3(NB * NC, 4), blk, 0, stream>>>(
            cbuf, xms, dbl, A_log, P, D_param, zbuf, cbuf /*Y over delta*/, L);
        // 10. out_proj: o = y @ out_proj_w^T        (MR x 512), K=1024
        gemm_kernel<128,128,16,8,8,0><<<dim3(4, MR/128), blk, 0, stream>>>(
            cbuf, 1024, out_proj_w, 1024, nullptr, ubuf, 512, MR, 512, 1024);
        // 11. dec1: h2 = relu(o @ dec_w1^T + b1)    (MR x 256), K=512
        gemm_kernel<128,128,16,8,8,1><<<dim3(2, MR/128), blk, 0, stream>>>(
            ubuf, 512, dec_w1, 512, dec_b1, hbuf, 256, MR, 256, 512);
        // 12. dec2: out = h2 @ dec_w2^T + b2        (MR x 64), K=256
        gemm_kernel<64,64,16,4,4,0><<<dim3(1, MR/64), blk, 0, stream>>>(
            hbuf, 256, dec_w2, 256, dec_b2, outp, 64, MR, 64, 256);
    }
}

// Round 4
// 620.350 us; speedup vs baseline: 2.5081x; 2.5081x over previous
//
#include <hip/hip_runtime.h>
#include <hip/hip_bf16.h>

typedef __attribute__((ext_vector_type(8))) short bf16x8;
typedef __attribute__((ext_vector_type(4))) float f32x4;
typedef __hip_bfloat16 bf16;

#define DEV __device__ __forceinline__
DEV float sigmoidf_(float x) { return 1.0f / (1.0f + __expf(-x)); }
DEV float bf2f(bf16 v) { return __bfloat162float(v); }
DEV bf16  f2bf(float v) { return __float2bfloat16(v); }

typedef const __attribute__((address_space(1))) void* gptr_t;
typedef __attribute__((address_space(3))) void* lptr_t;

// ---------------------------------------------------------------------------
// bf16 MFMA GEMM: C[m][n] = act( sum_k A[m][k] * W[n][k] + bias[n] )
// BM=128, BK=32, 256 threads = 4 waves in 2x2 wave grid, 16x16x32 MFMA.
// Staging: global_load_lds 16B/lane, LINEAR LDS dest (HW requirement),
// source pre-swizzled with byte ^= (row&3)<<4 — bits 4-5 only, so the
// involution stays inside each 64-byte BK-row (bug fixed vs (row&7)<<4
// which leaked into bit 6 = the next row). ds_read_b128 applies the same
// XOR => correct data, <=4-way bank conflict.
// ACT: 0 none, 1 relu, 2 softplus. OUTBF: 1 bf16 out, 0 f32 out.
// Requires: M % 128 == 0, N % BN == 0, K % 32 == 0, rows 16B-aligned.
// ---------------------------------------------------------------------------
template<int BN, int ACT, int OUTBF>
__global__ __launch_bounds__(256)
void gemm_mfma(const bf16* __restrict__ A, int lda,
               const bf16* __restrict__ W, int ldw,
               const float* __restrict__ bias,
               void* __restrict__ Cp, int ldc, int K)
{
    constexpr int BM = 128, BK = 32;
    constexpr int WN = BN / 2;
    constexpr int FM = 4, FN = WN / 16;
    constexpr int AITER = (BM * BK * 2) / (256 * 16);   // 2
    constexpr int BITER = (BN * BK * 2) / (256 * 16);   // 2 (BN=128) / 1 (BN=64)

    __shared__ __align__(16) ushort As[BM * BK];
    __shared__ __align__(16) ushort Bs[BN * BK];

    const int tid = threadIdx.x;
    const int lane = tid & 63;
    const int wid = tid >> 6;
    const int wm = wid >> 1, wn = wid & 1;
    const long m0 = (long)blockIdx.y * BM;
    const long n0 = (long)blockIdx.x * BN;

    f32x4 acc[FM][FN] = {};

    // staging chunk q -> (row, pre-swizzled in-row byte)
    int arow[AITER], acol[AITER];
#pragma unroll
    for (int it = 0; it < AITER; ++it) {
        int q = it * 256 + tid;
        int r = q >> 2;
        arow[it] = r;
        acol[it] = ((q & 3) * 16) ^ ((r & 3) << 4);
    }
    int brow[BITER], bcol[BITER];
#pragma unroll
    for (int it = 0; it < BITER; ++it) {
        int q = it * 256 + tid;
        int r = q >> 2;
        brow[it] = r;
        bcol[it] = ((q & 3) * 16) ^ ((r & 3) << 4);
    }

    const int fr = lane & 15, fq = lane >> 4;
    const int swz = (fr & 3) << 4;

    for (int k0 = 0; k0 < K; k0 += BK) {
#pragma unroll
        for (int it = 0; it < AITER; ++it) {
            const char* src = (const char*)A +
                ((size_t)(m0 + arow[it]) * lda + k0) * 2 + acol[it];
            __builtin_amdgcn_global_load_lds(
                (gptr_t)src,
                (lptr_t)((char*)As + (it * 256 + wid * 64) * 16), 16, 0, 0);
        }
#pragma unroll
        for (int it = 0; it < BITER; ++it) {
            const char* src = (const char*)W +
                ((size_t)(n0 + brow[it]) * ldw + k0) * 2 + bcol[it];
            __builtin_amdgcn_global_load_lds(
                (gptr_t)src,
                (lptr_t)((char*)Bs + (it * 256 + wid * 64) * 16), 16, 0, 0);
        }
        __syncthreads();   // drains vmcnt before barrier

        bf16x8 av[FM], bv[FN];
#pragma unroll
        for (int fm = 0; fm < FM; ++fm) {
            int ra = wm * 64 + fm * 16 + fr;
            av[fm] = *(const bf16x8*)((const char*)As + ra * 64 + ((fq * 16) ^ swz));
        }
#pragma unroll
        for (int fn = 0; fn < FN; ++fn) {
            int rb = wn * WN + fn * 16 + fr;
            bv[fn] = *(const bf16x8*)((const char*)Bs + rb * 64 + ((fq * 16) ^ swz));
        }
#pragma unroll
        for (int fm = 0; fm < FM; ++fm)
#pragma unroll
            for (int fn = 0; fn < FN; ++fn)
                acc[fm][fn] = __builtin_amdgcn_mfma_f32_16x16x32_bf16(
                    av[fm], bv[fn], acc[fm][fn], 0, 0, 0);
        __syncthreads();
    }

    // epilogue: D lane map col = lane&15, row = (lane>>4)*4 + r
#pragma unroll
    for (int fn = 0; fn < FN; ++fn) {
        long col = n0 + wn * WN + fn * 16 + fr;
        float bb = bias ? bias[col] : 0.0f;
#pragma unroll
        for (int fm = 0; fm < FM; ++fm) {
            long row0 = m0 + wm * 64 + fm * 16 + fq * 4;
#pragma unroll
            for (int r = 0; r < 4; ++r) {
                float v = acc[fm][fn][r] + bb;
                if (ACT == 1) v = fmaxf(v, 0.0f);
                else if (ACT == 2) v = fmaxf(v, 0.0f) + log1pf(__expf(-fabsf(v)));
                size_t o = (size_t)(row0 + r) * ldc + col;
                if (OUTBF) ((bf16*)Cp)[o] = f2bf(v);
                else       ((float*)Cp)[o] = v;
            }
        }
    }
}

// ---------------------------------------------------------------------------
// fp32 -> bf16 casts (weights + x), one launch, 9 jobs
// ---------------------------------------------------------------------------
struct CastJobs {
    const float* src[9];
    bf16* dst[9];
    int n[9];
};

__global__ __launch_bounds__(256)
void cast_bf16_kernel(CastJobs J)
{
    const int seg = blockIdx.y;
    const float* s = J.src[seg];
    bf16* d = J.dst[seg];
    const int n = J.n[seg];
    for (int i = blockIdx.x * 256 + threadIdx.x; i < n; i += gridDim.x * 256)
        d[i] = f2bf(s[i]);
}

#define CHUNK 32
#define DSTATE 16

// ---------------------------------------------------------------------------
// Depthwise causal conv (k=4) + bias + silu. f32 in (xm_raw), bf16 out.
// ---------------------------------------------------------------------------
__global__ __launch_bounds__(256)
void conv_silu_kernel(const float* __restrict__ xmr, const float* __restrict__ cw,
                      const float* __restrict__ cb, bf16* __restrict__ xms, int L)
{
    const int NC = L / CHUNK;
    const int c = blockIdx.x % NC;
    const int b = blockIdx.x / NC;
    const int d = blockIdx.y * 256 + threadIdx.x;

    const float w0 = cw[d * 4 + 0], w1 = cw[d * 4 + 1];
    const float w2 = cw[d * 4 + 2], w3 = cw[d * 4 + 3];
    const float bb = cb[d];

    const int t0 = c * CHUNK;
    float x0 = 0.f, x1 = 0.f, x2 = 0.f;
    if (t0 >= 3) {
        x0 = xmr[(size_t)(b * L + t0 - 3) * 1024 + d];
        x1 = xmr[(size_t)(b * L + t0 - 2) * 1024 + d];
        x2 = xmr[(size_t)(b * L + t0 - 1) * 1024 + d];
    }
    for (int t = t0; t < t0 + CHUNK; ++t) {
        float x3 = xmr[(size_t)(b * L + t) * 1024 + d];
        float v = fmaf(w0, x0, fmaf(w1, x1, fmaf(w2, x2, fmaf(w3, x3, bb))));
        xms[(size_t)(b * L + t) * 1024 + d] = f2bf(v * sigmoidf_(v));
        x0 = x1; x1 = x2; x2 = x3;
    }
}

// ---------------------------------------------------------------------------
// Scan pass 1: per chunk, P = prod(dA), S = local scan end. f32 state.
// delta f32; xms bf16; B from dblb bf16.
// ---------------------------------------------------------------------------
__global__ __launch_bounds__(256)
void scan_pass1(const float* __restrict__ delta, const bf16* __restrict__ xms,
                const bf16* __restrict__ dblb, const float* __restrict__ A_log,
                float* __restrict__ P, float* __restrict__ S, int L)
{
    const int NC = L / CHUNK;
    const int c = blockIdx.x % NC;
    const int b = blockIdx.x / NC;
    const int d = blockIdx.y * 256 + threadIdx.x;

    __shared__ float Bsh[CHUNK][DSTATE];
#pragma unroll
    for (int it = 0; it < 2; ++it) {
        int idx = threadIdx.x + it * 256;
        int t = idx >> 4, s = idx & 15;
        Bsh[t][s] = bf2f(dblb[(size_t)(b * L + c * CHUNK + t) * 64 + 32 + s]);
    }
    __syncthreads();

    float As_[DSTATE];
#pragma unroll
    for (int s = 0; s < DSTATE; ++s) As_[s] = -expf(A_log[d * DSTATE + s]);

    float h[DSTATE], p[DSTATE];
#pragma unroll
    for (int s = 0; s < DSTATE; ++s) { h[s] = 0.f; p[s] = 1.f; }

    for (int t = 0; t < CHUNK; ++t) {
        size_t row = (size_t)(b * L + c * CHUNK + t);
        float de = delta[row * 1024 + d];
        float x  = bf2f(xms[row * 1024 + d]);
        float dx = de * x;
#pragma unroll
        for (int s = 0; s < DSTATE; ++s) {
            float dA = __expf(de * As_[s]);
            h[s] = fmaf(dA, h[s], dx * Bsh[t][s]);
            p[s] *= dA;
        }
    }
#pragma unroll
    for (int s = 0; s < DSTATE; ++s) {
        size_t o = ((size_t)(b * NC + c) * DSTATE + s) * 1024 + d;
        P[o] = p[s];
        S[o] = h[s];
    }
}

// ---------------------------------------------------------------------------
// Pass 2: serial combine over chunks, Hinit in place of P (read-before-write).
// ---------------------------------------------------------------------------
__global__ __launch_bounds__(256)
void scan_pass2(const float* P, const float* __restrict__ S, float* Hinit, int NC)
{
    int g = blockIdx.x * 256 + threadIdx.x;
    int d = g & 1023;
    int s = (g >> 10) & 15;
    int b = g >> 14;
    float h = 0.f;
    for (int c = 0; c < NC; ++c) {
        size_t o = ((size_t)(b * NC + c) * DSTATE + s) * 1024 + d;
        float p  = P[o];
        float sv = S[o];
        Hinit[o] = h;              // overwrites P[o] AFTER both loads
        h = fmaf(p, h, sv);
    }
}

// ---------------------------------------------------------------------------
// Pass 3: recompute local scan, y = (sum_s h*C + xm*D) * silu(z), bf16 out.
// Y aliases the (dead) xm_raw f32 buffer.
// ---------------------------------------------------------------------------
__global__ __launch_bounds__(256)
void scan_pass3(const float* __restrict__ delta, const bf16* __restrict__ xms,
                const bf16* __restrict__ dblb, const float* __restrict__ A_log,
                const float* __restrict__ Hinit, const float* __restrict__ Dp,
                const bf16* __restrict__ zb, bf16* __restrict__ Y, int L)
{
    const int NC = L / CHUNK;
    const int c = blockIdx.x % NC;
    const int b = blockIdx.x / NC;
    const int d = blockIdx.y * 256 + threadIdx.x;

    __shared__ float Bsh[CHUNK][DSTATE];
    __shared__ float Csh[CHUNK][DSTATE];
#pragma unroll
    for (int it = 0; it < 2; ++it) {
        int idx = threadIdx.x + it * 256;
        int t = idx >> 4, s = idx & 15;
        size_t base = (size_t)(b * L + c * CHUNK + t) * 64;
        Bsh[t][s] = bf2f(dblb[base + 32 + s]);
        Csh[t][s] = bf2f(dblb[base + 48 + s]);
    }
    __syncthreads();

    float As_[DSTATE];
#pragma unroll
    for (int s = 0; s < DSTATE; ++s) As_[s] = -expf(A_log[d * DSTATE + s]);

    float h[DSTATE];
#pragma unroll
    for (int s = 0; s < DSTATE; ++s)
        h[s] = Hinit[((size_t)(b * NC + c) * DSTATE + s) * 1024 + d];

    const float Dd = Dp[d];
    for (int t = 0; t < CHUNK; ++t) {
        size_t row = (size_t)(b * L + c * CHUNK + t);
        float de = delta[row * 1024 + d];
        float x  = bf2f(xms[row * 1024 + d]);
        float dx = de * x;
        float y = 0.f;
#pragma unroll
        for (int s = 0; s < DSTATE; ++s) {
            float dA = __expf(de * As_[s]);
            h[s] = fmaf(dA, h[s], dx * Bsh[t][s]);
            y = fmaf(h[s], Csh[t][s], y);
        }
        y = fmaf(x, Dd, y);
        float z = bf2f(zb[row * 1024 + d]);
        Y[row * 1024 + d] = f2bf(y * (z * sigmoidf_(z)));
    }
}

// ---------------------------------------------------------------------------

extern "C" void kernel_launch(void* const* d_in, const int* in_sizes, int n_in,
                              void* d_out, int out_size, void* d_ws, size_t ws_size,
                              hipStream_t stream)
{
    (void)in_sizes; (void)n_in; (void)out_size;

    const float* x         = (const float*)d_in[0];
    const float* enc_w1    = (const float*)d_in[1];
    const float* enc_b1    = (const float*)d_in[2];
    const float* enc_w2    = (const float*)d_in[3];
    const float* enc_b2    = (const float*)d_in[4];
    const float* in_proj_w = (const float*)d_in[5];
    const float* conv_w    = (const float*)d_in[6];
    const float* conv_b    = (const float*)d_in[7];
    const float* x_proj_w  = (const float*)d_in[8];
    const float* dt_proj_w = (const float*)d_in[9];
    const float* dt_proj_b = (const float*)d_in[10];
    const float* A_log     = (const float*)d_in[11];
    const float* D_param   = (const float*)d_in[12];
    const float* out_proj_w= (const float*)d_in[13];
    const float* dec_w1    = (const float*)d_in[14];
    const float* dec_b1    = (const float*)d_in[15];
    const float* dec_w2    = (const float*)d_in[16];
    const float* dec_b2    = (const float*)d_in[17];
    float* out = (float*)d_out;

    const int L = 2048, NC = 64;

    // ---- bf16 fixed region (weights + x), element offsets ----
    bf16* wb = (bf16*)d_ws;
    size_t off = 0;
    bf16* w_enc1 = wb + off; off += 16384;      // 256x64
    bf16* w_enc2 = wb + off; off += 131072;     // 512x256
    bf16* w_inpj = wb + off; off += 1048576;    // 2048x512
    bf16* w_xprj = wb + off; off += 65536;      // 64x1024
    bf16* w_dtpj = wb + off; off += 32768;      // 1024x32
    bf16* w_outp = wb + off; off += 524288;     // 512x1024
    bf16* w_dec1 = wb + off; off += 131072;     // 256x512
    bf16* w_dec2 = wb + off; off += 16384;      // 64x256
    bf16* xbf    = wb + off; off += 1048576;    // 16384x64
    const size_t fixedB = off * 2;              // 6,029,312 bytes

    // per-row bytes: bf16{256+512+1024+1024+64} + f32{1024+1024+512+512}
    //              = 5760 B (bf16 part) + 12288 B (f32 part) = 18048 B
    const size_t PER_ROW = 18048;
    int SPLIT = 8;
    if      (fixedB + (size_t)16384 * PER_ROW <= ws_size) SPLIT = 1;
    else if (fixedB + (size_t) 8192 * PER_ROW <= ws_size) SPLIT = 2;
    else if (fixedB + (size_t) 4096 * PER_ROW <= ws_size) SPLIT = 4;

    const int NB = 8 / SPLIT;
    const int MR = NB * L;

    char* pb = (char*)d_ws + fixedB;
    bf16*  hbf   = (bf16*)pb;                        // MR x 256  (reused: h2)
    bf16*  ubf   = hbf + (size_t)MR * 256;           // MR x 512  (reused: o)
    bf16*  zbf   = ubf + (size_t)MR * 512;           // MR x 1024
    bf16*  xms   = zbf + (size_t)MR * 1024;          // MR x 1024
    bf16*  dblb  = xms + (size_t)MR * 1024;          // MR x 64
    float* xmraw = (float*)(dblb + (size_t)MR * 64); // MR x 1024 f32 (-> y bf16)
    float* delt  = xmraw + (size_t)MR * 1024;        // MR x 1024 f32
    float* Pf    = delt  + (size_t)MR * 1024;        // MR x 512 f32 (-> Hinit)
    float* Sf    = Pf    + (size_t)MR * 512;         // MR x 512 f32

    // ---- casts (weights + x), every call ----
    CastJobs J;
    J.src[0] = enc_w1;     J.dst[0] = w_enc1; J.n[0] = 16384;
    J.src[1] = enc_w2;     J.dst[1] = w_enc2; J.n[1] = 131072;
    J.src[2] = in_proj_w;  J.dst[2] = w_inpj; J.n[2] = 1048576;
    J.src[3] = x_proj_w;   J.dst[3] = w_xprj; J.n[3] = 65536;
    J.src[4] = dt_proj_w;  J.dst[4] = w_dtpj; J.n[4] = 32768;
    J.src[5] = out_proj_w; J.dst[5] = w_outp; J.n[5] = 524288;
    J.src[6] = dec_w1;     J.dst[6] = w_dec1; J.n[6] = 131072;
    J.src[7] = dec_w2;     J.dst[7] = w_dec2; J.n[7] = 16384;
    J.src[8] = x;          J.dst[8] = xbf;    J.n[8] = 1048576;
    cast_bf16_kernel<<<dim3(128, 9), 256, 0, stream>>>(J);

    dim3 blk(256);
    for (int p = 0; p < SPLIT; ++p) {
        const bf16* xp  = xbf + (size_t)p * MR * 64;
        float*     outp = out + (size_t)p * MR * 64;

        // enc1: relu(x @ enc_w1^T + b1) -> h (MR x 256), K=64
        gemm_mfma<128,1,1><<<dim3(2, MR/128), blk, 0, stream>>>(
            xp, 64, w_enc1, 64, enc_b1, hbf, 256, 64);
        // enc2: u = h @ enc_w2^T + b2 (MR x 512), K=256
        gemm_mfma<128,0,1><<<dim3(4, MR/128), blk, 0, stream>>>(
            hbf, 256, w_enc2, 256, enc_b2, ubf, 512, 256);
        // in_proj xm half (MR x 1024 f32), K=512
        gemm_mfma<128,0,0><<<dim3(8, MR/128), blk, 0, stream>>>(
            ubf, 512, w_inpj, 512, nullptr, xmraw, 1024, 512);
        // in_proj z half (MR x 1024 bf16)
        gemm_mfma<128,0,1><<<dim3(8, MR/128), blk, 0, stream>>>(
            ubf, 512, w_inpj + (size_t)1024 * 512, 512, nullptr, zbf, 1024, 512);
        // conv + silu -> xms (bf16)
        conv_silu_kernel<<<dim3(NB * NC, 4), blk, 0, stream>>>(
            xmraw, conv_w, conv_b, xms, L);
        // x_proj: dbl = xms @ x_proj_w^T (MR x 64 bf16), K=1024
        gemm_mfma<64,0,1><<<dim3(1, MR/128), blk, 0, stream>>>(
            xms, 1024, w_xprj, 1024, nullptr, dblb, 64, 1024);
        // dt_proj + softplus: delta (MR x 1024 f32), K=32
        gemm_mfma<128,2,0><<<dim3(8, MR/128), blk, 0, stream>>>(
            dblb, 64, w_dtpj, 32, dt_proj_b, delt, 1024, 32);
        // selective scan
        scan_pass1<<<dim3(NB * NC, 4), blk, 0, stream>>>(
            delt, xms, dblb, A_log, Pf, Sf, L);
        scan_pass2<<<dim3(NB * 64), blk, 0, stream>>>(Pf, Sf, Pf, NC);
        scan_pass3<<<dim3(NB * NC, 4), blk, 0, stream>>>(
            delt, xms, dblb, A_log, Pf, D_param, zbf, (bf16*)xmraw /*y*/, L);
        // out_proj: o = y @ out_proj_w^T (MR x 512 bf16), K=1024
        gemm_mfma<128,0,1><<<dim3(4, MR/128), blk, 0, stream>>>(
            (const bf16*)xmraw, 1024, w_outp, 1024, nullptr, ubf, 512, 1024);
        // dec1: relu(o @ dec_w1^T + b1) (MR x 256 bf16), K=512
        gemm_mfma<128,1,1><<<dim3(2, MR/128), blk, 0, stream>>>(
            ubf, 512, w_dec1, 512, dec_b1, hbf, 256, 512);
        // dec2: out = h2 @ dec_w2^T + b2 (MR x 64 f32), K=256
        gemm_mfma<64,0,0><<<dim3(1, MR/128), blk, 0, stream>>>(
            hbf, 256, w_dec2, 256, dec_b2, outp, 64, 256);
    }
}